// Round 2
// baseline (1166.675 us; speedup 1.0000x reference)
//
#include <hip/hip_runtime.h>
#include <stdint.h>

// ---------------------------------------------------------------------------
// QuantumQLSTM: T=2048, B=512, D=128, H=128, NQ=8.  FP32 inputs/outputs.
// Structure (validated vs harness ref magnitudes in R0):
//   * gates are per-sample scalars -> h[b,:], c[b,:] constant across H ->
//     recurrence is per-b SCALAR; h feedback enters z as h * sum_d W[q,128+d].
//   * qgate(z) = mean(sin^2(z/2)) = 0.5 - sum_q cos(z_q)/16
// K1: x-projection GEMM (fp32 via hi/lo bf16 split, 3 MFMAs) ->
//     Z[t,b,q] = fract((x.Wx + bias)/2pi) stored fp16 in d_ws (67 MB).
// K2: 512 scalar scans (2 per wave), gate cross-talk via DPP + ds_bpermute,
//     writes fp32 out rows (h broadcast across H) + final hx, cx.
// ---------------------------------------------------------------------------

typedef __attribute__((ext_vector_type(8))) short short8;
typedef __attribute__((ext_vector_type(4))) float float4v;

#define TSTEPS 2048
#define BATCH  512
#define DIMX   128
#define HID    128
#define ROWS   (TSTEPS * BATCH)   // 1048576

__device__ __forceinline__ float bf2f(unsigned short u) {
  union { unsigned int i; float f; } v; v.i = ((unsigned int)u) << 16; return v.f;
}
__device__ __forceinline__ unsigned short f2bf(float f) {
  union { float f; unsigned int i; } v; v.f = f;
  unsigned int u = v.i;
  return (unsigned short)((u + 0x7FFFu + ((u >> 16) & 1u)) >> 16);
}

// load 8 contiguous fp32, split each into hi+lo bf16 (x = hi + lo exactly in
// fp32; lo rounding leaves ~2^-16 relative residual)
__device__ __forceinline__ void split8(const float* __restrict__ p,
                                       short8& hi, short8& lo) {
  float4v a = *(const float4v*)p;
  float4v b = *(const float4v*)(p + 4);
#pragma unroll
  for (int j = 0; j < 8; ++j) {
    float x = (j < 4) ? a[j] : b[j - 4];
    unsigned short h = f2bf(x);
    float r = x - bf2f(h);
    hi[j] = (short)h;
    lo[j] = (short)f2bf(r);
  }
}

// ---------------------------------------------------------------------------
// K1: grid = ROWS/64 blocks, 256 thr (4 waves x 16 rows).
// mfma_f32_16x16x32_bf16: A[m=lane&15][k=quad*8+j]; B[k][n=lane&15];
// C/D: col=lane&15, row=quad*4+reg.  N=32 cols = [f(8) i(8) | u(8) o(8)].
// ---------------------------------------------------------------------------
__global__ __launch_bounds__(256) void qlstm_gemm(
    const float* __restrict__ X,
    const float* __restrict__ Wf, const float* __restrict__ bfv,
    const float* __restrict__ Wi, const float* __restrict__ biv,
    const float* __restrict__ Wu, const float* __restrict__ buv,
    const float* __restrict__ Wo, const float* __restrict__ bov,
    _Float16* __restrict__ Z)
{
  const int lane = threadIdx.x & 63;
  const int wave = threadIdx.x >> 6;
  const int m    = lane & 15;
  const int quad = lane >> 4;
  const long row0 = ((long)blockIdx.x * 4 + wave) * 16;

  const int q = m & 7;
  const float* b0 = (m < 8) ? Wf : Wi;   // cols 0..15  -> f,i
  const float* b1 = (m < 8) ? Wu : Wo;   // cols 16..31 -> u,o

  short8 b0h[4], b0l[4], b1h[4], b1l[4];
#pragma unroll
  for (int ks = 0; ks < 4; ++ks) {
    split8(b0 + q * 256 + ks * 32 + quad * 8, b0h[ks], b0l[ks]);
    split8(b1 + q * 256 + ks * 32 + quad * 8, b1h[ks], b1l[ks]);
  }

  float4v acc0 = {0.f, 0.f, 0.f, 0.f};
  float4v acc1 = {0.f, 0.f, 0.f, 0.f};
  const float* xrow = X + (row0 + m) * DIMX;
#pragma unroll
  for (int ks = 0; ks < 4; ++ks) {
    short8 ah, al;
    split8(xrow + ks * 32 + quad * 8, ah, al);
    acc0 = __builtin_amdgcn_mfma_f32_16x16x32_bf16(ah, b0h[ks], acc0, 0, 0, 0);
    acc0 = __builtin_amdgcn_mfma_f32_16x16x32_bf16(al, b0h[ks], acc0, 0, 0, 0);
    acc0 = __builtin_amdgcn_mfma_f32_16x16x32_bf16(ah, b0l[ks], acc0, 0, 0, 0);
    acc1 = __builtin_amdgcn_mfma_f32_16x16x32_bf16(ah, b1h[ks], acc1, 0, 0, 0);
    acc1 = __builtin_amdgcn_mfma_f32_16x16x32_bf16(al, b1h[ks], acc1, 0, 0, 0);
    acc1 = __builtin_amdgcn_mfma_f32_16x16x32_bf16(ah, b1l[ks], acc1, 0, 0, 0);
  }

  const float INV2PI = 0.15915494309189535f;
  const float bias0 = ((m < 8) ? bfv : biv)[q];
  const float bias1 = ((m < 8) ? buv : bov)[q];
#pragma unroll
  for (int r = 0; r < 4; ++r) {
    long row = row0 + quad * 4 + r;
    float z0 = __builtin_amdgcn_fractf((acc0[r] + bias0) * INV2PI);
    float z1 = __builtin_amdgcn_fractf((acc1[r] + bias1) * INV2PI);
    Z[row * 32 + m]      = (_Float16)z0;   // cos is periodic: keep fract only
    Z[row * 32 + 16 + m] = (_Float16)z1;
  }
}

// ---------------------------------------------------------------------------
// K2: scan. 256 blocks x 64 threads. lane&31 = gate*8 + wire; lane>>5 picks
// one of 2 batch rows per wave.
// ---------------------------------------------------------------------------
template <int CTRL>
__device__ __forceinline__ float dppf(float x) {
  return __int_as_float(
      __builtin_amdgcn_mov_dpp(__float_as_int(x), CTRL, 0xF, 0xF, true));
}

__global__ __launch_bounds__(64) void qlstm_scan(
    const _Float16* __restrict__ Z,
    const float* __restrict__ Wf, const float* __restrict__ Wi,
    const float* __restrict__ Wu, const float* __restrict__ Wo,
    float* __restrict__ out)
{
  const int lane = threadIdx.x;            // 0..63
  const int g32  = lane & 31;
  const int gate = g32 >> 3;               // 0:f 1:i 2:u 3:o
  const int q    = g32 & 7;
  const int b    = blockIdx.x * 2 + (lane >> 5);

  // whsum = sum over hidden half of this wire's weight row
  const float* Wsel = (gate == 0) ? Wf : (gate == 1) ? Wi
                    : (gate == 2) ? Wu : Wo;
  const float* wp = Wsel + q * 256 + 128;
  float ws = 0.f;
#pragma unroll 8
  for (int j = 0; j < 128; ++j) ws += wp[j];
  const float INV2PI = 0.15915494309189535f;
  const float wrev = ws * INV2PI;          // h coefficient, revolutions

  // sigmoid for f,i,o ; tanh(p)=2*sigmoid(2p)-1 for u.
  // p = 0.5 - s/16  ->  -p*log2e = s*(L/16) - L/2 ; tanh arg doubles both.
  const float L2E = 1.4426950408889634f;
  const float ka = (gate == 2) ? (L2E / 8.f)  : (L2E / 16.f);
  const float kb = (gate == 2) ? (-L2E)       : (-0.5f * L2E);
  const float s2 = (gate == 2) ? 2.f : 1.f;
  const float s3 = (gate == 2) ? -1.f : 0.f;

  const int base32 = lane & 32;            // bpermute byte addrs per gate
  const int adr_f = (base32 + 0  + q) * 4;
  const int adr_i = (base32 + 8  + q) * 4;
  const int adr_u = (base32 + 16 + q) * 4;
  const int adr_o = (base32 + 24 + q) * 4;

  float c = 0.f, h = 0.f;

  const _Float16* zp = Z + (long)b * 32 + g32;   // per-t stride 512*32
  _Float16 zr[8];
#pragma unroll
  for (int j = 0; j < 8; ++j) zr[j] = zp[(long)j * 16384];

  float* orow = out + (long)b * HID + g32 * 4;   // per-t stride 65536 fp32

  for (int tt = 0; tt < TSTEPS; tt += 8) {
#pragma unroll
    for (int j = 0; j < 8; ++j) {
      const int t = tt + j;
      float zx = (float)zr[j];
      int tn = t + 8; if (tn > TSTEPS - 1) tn = TSTEPS - 1;
      zr[j] = zp[(long)tn * 16384];              // prefetch 8 ahead

      float r  = __builtin_fmaf(h, wrev, zx);
      r        = __builtin_amdgcn_fractf(r);
      float cs = __builtin_amdgcn_cosf(r);       // cos(2*pi*r)

      // sum over the 8 wires of this gate: xor7, xor1, xor2 butterfly
      float s = cs + dppf<0x141>(cs);            // row_half_mirror (xor 7)
      s += dppf<0xB1>(s);                        // quad_perm [1,0,3,2] (xor 1)
      s += dppf<0x4E>(s);                        // quad_perm [2,3,0,1] (xor 2)

      float e = __builtin_amdgcn_exp2f(__builtin_fmaf(s, ka, kb));
      float v = __builtin_fmaf(__builtin_amdgcn_rcpf(1.f + e), s2, s3);

      float fg = __int_as_float(__builtin_amdgcn_ds_bpermute(adr_f, __float_as_int(v)));
      float ig = __int_as_float(__builtin_amdgcn_ds_bpermute(adr_i, __float_as_int(v)));
      float ug = __int_as_float(__builtin_amdgcn_ds_bpermute(adr_u, __float_as_int(v)));
      float og = __int_as_float(__builtin_amdgcn_ds_bpermute(adr_o, __float_as_int(v)));

      c = __builtin_fmaf(fg, c, ig * ug);
      float e2 = __builtin_amdgcn_exp2f(c * (2.f * L2E));
      float th = __builtin_fmaf(-2.f, __builtin_amdgcn_rcpf(1.f + e2), 1.f);
      h = og * th;

      float4v hv = {h, h, h, h};
      *(float4v*)(orow + (long)t * (BATCH * HID)) = hv;  // 4 fp32 per lane
    }
  }

  // finals: hx then cx, each [B, H] fp32
  float4v hv = {h, h, h, h};
  float4v cv = {c, c, c, c};
  float* hxp = out + (long)TSTEPS * (BATCH * HID) + (long)b * HID + g32 * 4;
  *(float4v*)hxp = hv;
  *(float4v*)(hxp + BATCH * HID) = cv;
}

// ---------------------------------------------------------------------------
extern "C" void kernel_launch(void* const* d_in, const int* in_sizes, int n_in,
                              void* d_out, int out_size, void* d_ws, size_t ws_size,
                              hipStream_t stream) {
  (void)in_sizes; (void)n_in; (void)out_size; (void)ws_size;
  const float* X   = (const float*)d_in[0];
  const float* Wf  = (const float*)d_in[1];
  const float* bfv = (const float*)d_in[2];
  const float* Wi  = (const float*)d_in[3];
  const float* biv = (const float*)d_in[4];
  const float* Wu  = (const float*)d_in[5];
  const float* buv = (const float*)d_in[6];
  const float* Wo  = (const float*)d_in[7];
  const float* bov = (const float*)d_in[8];

  _Float16* Z = (_Float16*)d_ws;           // ROWS*32 fp16 = 67,108,864 B
  float* out = (float*)d_out;

  qlstm_gemm<<<ROWS / 64, 256, 0, stream>>>(X, Wf, bfv, Wi, biv, Wu, buv, Wo, bov, Z);
  qlstm_scan<<<BATCH / 2, 64, 0, stream>>>(Z, Wf, Wi, Wu, Wo, out);
}

// Round 3
// 992.960 us; speedup vs baseline: 1.1749x; 1.1749x over previous
//
#include <hip/hip_runtime.h>
#include <stdint.h>

// ---------------------------------------------------------------------------
// QuantumQLSTM fused: T=2048, B=512, D=128, H=128, NQ=8.  FP32 in/out.
// One kernel, 256 blocks x 64 threads (1 wave/block, ~1 wave/CU).
// Each wave owns 2 batch rows. Per 8-step t-block it:
//   * prefetches next 16 X rows (8t x 2b) as MFMA A-fragments (1 block ahead)
//   * computes zx = (x.Wx + bias)/2pi via hi/lo-split bf16 MFMA (fp32 acc)
//   * stages zx in a 4KB LDS double buffer (single wave: no barriers)
//   * runs the serial scalar recurrence 8 steps off LDS
// Recurrence (validated R2, absmax 9.8e-4):
//   qgate = 0.5 - sum_q cos(2pi*(zx_q + h*wsum_q/2pi))/16, per-gate sigmoid/
//   tanh, c = f*c + i*g, h = o*tanh(c); h broadcast across H for the output.
// The GEMM work (~120 cyc/step issue) hides inside the ~400 cyc/step serial
// chain stalls (R2: VALUBusy 8%).
// ---------------------------------------------------------------------------

typedef __attribute__((ext_vector_type(8))) short short8;
typedef __attribute__((ext_vector_type(4))) float float4v;

#define TSTEPS 2048
#define BATCH  512
#define DIMX   128
#define HID    128
#define TBLK   (TSTEPS / 8)      // 256 t-blocks
#define LROW   33                // LDS row pitch (pad +1: conflict-free)
#define LBUF   (16 * LROW)       // 528 floats per buffer

template <int CTRL>
__device__ __forceinline__ float dppf(float x) {
  return __int_as_float(
      __builtin_amdgcn_mov_dpp(__float_as_int(x), CTRL, 0xF, 0xF, true));
}

// split 8 fp32 into truncated-hi + truncated-lo bf16 (err ~2^-16 relative)
__device__ __forceinline__ void splitv(float4v a, float4v b,
                                       short8& hi, short8& lo) {
#pragma unroll
  for (int j = 0; j < 8; ++j) {
    float x = (j < 4) ? a[j] : b[j - 4];
    unsigned int u = __float_as_uint(x);
    float r = x - __uint_as_float(u & 0xFFFF0000u);   // exact fp32 residual
    hi[j] = (short)(u >> 16);
    lo[j] = (short)(__float_as_uint(r) >> 16);
  }
}

__global__ __launch_bounds__(64) void qlstm_fused(
    const float* __restrict__ X,
    const float* __restrict__ Wf, const float* __restrict__ bfv,
    const float* __restrict__ Wi, const float* __restrict__ biv,
    const float* __restrict__ Wu, const float* __restrict__ buv,
    const float* __restrict__ Wo, const float* __restrict__ bov,
    float* __restrict__ out)
{
  __shared__ float Zl[2 * LBUF];

  const int lane  = threadIdx.x;        // 0..63
  const int m     = lane & 15;          // MFMA: A-row / C-col index
  const int quad  = lane >> 4;
  const int g32   = lane & 31;          // chain: gate*8 + wire
  const int gate  = g32 >> 3;
  const int q     = g32 & 7;
  const int bhalf = lane >> 5;
  const int b0    = blockIdx.x * 2;

  // ---- B fragments (weights, hi/lo split), biases -------------------------
  const int qm = m & 7;
  const float* Bt0 = (m < 8) ? Wf : Wi;     // C cols 0..15 -> f,i
  const float* Bt1 = (m < 8) ? Wu : Wo;     // C cols 16..31 -> u,o
  short8 b0h[4], b0l[4], b1h[4], b1l[4];
#pragma unroll
  for (int ks = 0; ks < 4; ++ks) {
    const float* p0 = Bt0 + qm * 256 + ks * 32 + quad * 8;
    const float* p1 = Bt1 + qm * 256 + ks * 32 + quad * 8;
    splitv(*(const float4v*)p0, *(const float4v*)(p0 + 4), b0h[ks], b0l[ks]);
    splitv(*(const float4v*)p1, *(const float4v*)(p1 + 4), b1h[ks], b1l[ks]);
  }
  const float INV2PI = 0.15915494309189535f;
  const float bias0 = ((m < 8) ? bfv : biv)[qm];
  const float bias1 = ((m < 8) ? buv : bov)[qm];

  // ---- chain constants ----------------------------------------------------
  const float* Wsel = (gate == 0) ? Wf : (gate == 1) ? Wi
                    : (gate == 2) ? Wu : Wo;
  const float* wp = Wsel + q * 256 + 128;
  float ws = 0.f;
#pragma unroll 8
  for (int j = 0; j < 128; ++j) ws += wp[j];
  const float wrev = ws * INV2PI;

  const float L2E = 1.4426950408889634f;
  const float ka = (gate == 2) ? (L2E / 8.f) : (L2E / 16.f);
  const float kb = (gate == 2) ? (-L2E)      : (-0.5f * L2E);
  const float s2 = (gate == 2) ? 2.f : 1.f;
  const float s3 = (gate == 2) ? -1.f : 0.f;

  const int base32 = lane & 32;
  const int adr_f = (base32 + 0  + q) * 4;
  const int adr_i = (base32 + 8  + q) * 4;
  const int adr_u = (base32 + 16 + q) * 4;
  const int adr_o = (base32 + 24 + q) * 4;

  // ---- A-fragment base: row m -> (t_local = m>>1, b = b0 + (m&1)) ---------
  const float* arow = X + ((long)(m >> 1) * BATCH + b0 + (m & 1)) * DIMX;
  float4v Aa[8];

#define LOADA(tb)                                                            \
  {                                                                          \
    const float* p_ = arow + (long)(tb) * (8 * BATCH * DIMX);                \
    _Pragma("unroll")                                                        \
    for (int ks_ = 0; ks_ < 4; ++ks_) {                                      \
      Aa[2 * ks_]     = *(const float4v*)(p_ + ks_ * 32 + quad * 8);         \
      Aa[2 * ks_ + 1] = *(const float4v*)(p_ + ks_ * 32 + quad * 8 + 4);     \
    }                                                                        \
  }

#define PRODUCE(buf)                                                         \
  {                                                                          \
    float4v acc0 = {0.f, 0.f, 0.f, 0.f};                                     \
    float4v acc1 = {0.f, 0.f, 0.f, 0.f};                                     \
    _Pragma("unroll")                                                        \
    for (int ks_ = 0; ks_ < 4; ++ks_) {                                      \
      short8 ah_, al_;                                                       \
      splitv(Aa[2 * ks_], Aa[2 * ks_ + 1], ah_, al_);                        \
      acc0 = __builtin_amdgcn_mfma_f32_16x16x32_bf16(ah_, b0h[ks_], acc0, 0, 0, 0); \
      acc0 = __builtin_amdgcn_mfma_f32_16x16x32_bf16(al_, b0h[ks_], acc0, 0, 0, 0); \
      acc0 = __builtin_amdgcn_mfma_f32_16x16x32_bf16(ah_, b0l[ks_], acc0, 0, 0, 0); \
      acc1 = __builtin_amdgcn_mfma_f32_16x16x32_bf16(ah_, b1h[ks_], acc1, 0, 0, 0); \
      acc1 = __builtin_amdgcn_mfma_f32_16x16x32_bf16(al_, b1h[ks_], acc1, 0, 0, 0); \
      acc1 = __builtin_amdgcn_mfma_f32_16x16x32_bf16(ah_, b1l[ks_], acc1, 0, 0, 0); \
    }                                                                        \
    _Pragma("unroll")                                                        \
    for (int r_ = 0; r_ < 4; ++r_) {                                         \
      int row_ = quad * 4 + r_;                                              \
      Zl[(buf) * LBUF + row_ * LROW + m]      = (acc0[r_] + bias0) * INV2PI; \
      Zl[(buf) * LBUF + row_ * LROW + m + 16] = (acc1[r_] + bias1) * INV2PI; \
    }                                                                        \
  }

  float c = 0.f, h = 0.f;
  float* orow = out + (long)(b0 + bhalf) * HID + g32 * 4;

  // prologue: fill buf0 with t-block 0, then prefetch t-block 1
  LOADA(0);
  PRODUCE(0);
  LOADA(1);

  for (int k = 0; k < TBLK; ++k) {
    // produce zx for t-block k+1 into the other buffer (A loaded last iter)
    PRODUCE((k + 1) & 1);
    int kn = k + 2; if (kn > TBLK - 1) kn = TBLK - 1;
    LOADA(kn);                                  // prefetch t-block k+2

    const float* zb = Zl + (k & 1) * LBUF + bhalf * LROW + g32;
#pragma unroll
    for (int j = 0; j < 8; ++j) {
      float zx = zb[j * 2 * LROW];

      float r  = __builtin_fmaf(h, wrev, zx);
      float cs = __builtin_amdgcn_cosf(r);      // cos(2*pi*r), |r| < ~1.2 rev

      float s = cs + dppf<0x141>(cs);           // xor7 (row_half_mirror)
      s += dppf<0xB1>(s);                       // xor1 (quad_perm 1,0,3,2)
      s += dppf<0x4E>(s);                       // xor2 (quad_perm 2,3,0,1)

      float e = __builtin_amdgcn_exp2f(__builtin_fmaf(s, ka, kb));
      float v = __builtin_fmaf(__builtin_amdgcn_rcpf(1.f + e), s2, s3);

      float fg = __int_as_float(__builtin_amdgcn_ds_bpermute(adr_f, __float_as_int(v)));
      float ig = __int_as_float(__builtin_amdgcn_ds_bpermute(adr_i, __float_as_int(v)));
      float ug = __int_as_float(__builtin_amdgcn_ds_bpermute(adr_u, __float_as_int(v)));
      float og = __int_as_float(__builtin_amdgcn_ds_bpermute(adr_o, __float_as_int(v)));

      c = __builtin_fmaf(fg, c, ig * ug);
      float e2 = __builtin_amdgcn_exp2f(c * (2.f * L2E));
      float th = __builtin_fmaf(-2.f, __builtin_amdgcn_rcpf(1.f + e2), 1.f);
      h = og * th;

      float4v hv = {h, h, h, h};
      *(float4v*)orow = hv;
      orow += (long)BATCH * HID;
    }
  }

  // finals: hx then cx, each [B, H]
  float4v hv = {h, h, h, h};
  float4v cv = {c, c, c, c};
  float* hxp = out + (long)TSTEPS * BATCH * HID + (long)(b0 + bhalf) * HID + g32 * 4;
  *(float4v*)hxp = hv;
  *(float4v*)(hxp + BATCH * HID) = cv;
#undef LOADA
#undef PRODUCE
}

// ---------------------------------------------------------------------------
extern "C" void kernel_launch(void* const* d_in, const int* in_sizes, int n_in,
                              void* d_out, int out_size, void* d_ws, size_t ws_size,
                              hipStream_t stream) {
  (void)in_sizes; (void)n_in; (void)out_size; (void)d_ws; (void)ws_size;
  const float* X   = (const float*)d_in[0];
  const float* Wf  = (const float*)d_in[1];
  const float* bfv = (const float*)d_in[2];
  const float* Wi  = (const float*)d_in[3];
  const float* biv = (const float*)d_in[4];
  const float* Wu  = (const float*)d_in[5];
  const float* buv = (const float*)d_in[6];
  const float* Wo  = (const float*)d_in[7];
  const float* bov = (const float*)d_in[8];
  float* out = (float*)d_out;

  qlstm_fused<<<BATCH / 2, 64, 0, stream>>>(X, Wf, bfv, Wi, biv, Wu, buv, Wo, bov, out);
}